// Round 1
// baseline (1317.154 us; speedup 1.0000x reference)
//
#include <hip/hip_runtime.h>
#include <hip/hip_bf16.h>

#define BATCH 8
#define CH 256
#define HWSZ 4096
#define NGROUPS 8
#define CPG 32
#define GSIZE (CPG * HWSZ)  // 131072 elements per (b, group)

typedef unsigned short u16;
typedef __bf16 bf16_t;
typedef short bf16x8 __attribute__((ext_vector_type(8)));   // 8 bf16 in 4 VGPRs
typedef float f32x4 __attribute__((ext_vector_type(4)));
typedef unsigned int u32x4 __attribute__((ext_vector_type(4)));

union Frag8 {
    bf16x8 v;
    u32x4 q;
    u16 s[8];
};

static __device__ inline u16 f2bf(float f) {
    unsigned int u = __float_as_uint(f);
    u = u + 0x7fffu + ((u >> 16) & 1u);   // round-to-nearest-even
    return (u16)(u >> 16);
}

// ---------------------------------------------------------------- GroupNorm stats
__global__ __launch_bounds__(256) void gn_stats_k(const float* __restrict__ x,
                                                  float* __restrict__ stats) {
    int bg = blockIdx.x;  // b*8+g ; group is contiguous slab of CPG*HWSZ floats
    const float4* base = (const float4*)(x + (size_t)bg * GSIZE);
    float s = 0.f, ss = 0.f;
    for (int i = threadIdx.x; i < GSIZE / 4; i += 256) {
        float4 v = base[i];
        s += v.x + v.y + v.z + v.w;
        ss += v.x * v.x + v.y * v.y + v.z * v.z + v.w * v.w;
    }
    #pragma unroll
    for (int off = 32; off > 0; off >>= 1) {
        s += __shfl_xor(s, off, 64);
        ss += __shfl_xor(ss, off, 64);
    }
    __shared__ float red[8];
    int wid = threadIdx.x >> 6;
    if ((threadIdx.x & 63) == 0) { red[wid * 2] = s; red[wid * 2 + 1] = ss; }
    __syncthreads();
    if (threadIdx.x == 0) {
        float S = red[0] + red[2] + red[4] + red[6];
        float SS = red[1] + red[3] + red[5] + red[7];
        float mean = S / (float)GSIZE;
        float var = SS / (float)GSIZE - mean * mean;
        stats[bg * 2] = mean;
        stats[bg * 2 + 1] = rsqrtf(var + 1e-5f);
    }
}

// ---------------------------------------------------------------- GroupNorm apply
// writes xn f32 [b][c][hw] (residual) and xn bf16 transposed [b][hw][c]
#define TPAD 258
__global__ __launch_bounds__(256) void gn_apply_k(const float* __restrict__ x,
                                                  const float* __restrict__ stats,
                                                  const float* __restrict__ gw,
                                                  const float* __restrict__ gb,
                                                  float* __restrict__ xnf,
                                                  u16* __restrict__ xnt) {
    int b = blockIdx.x >> 6;
    int hw0 = (blockIdx.x & 63) * 64;
    __shared__ u16 lds[64 * TPAD];
    __shared__ float sw[CH], sb[CH], smean[NGROUPS], srstd[NGROUPS];
    if (threadIdx.x < CH) { sw[threadIdx.x] = gw[threadIdx.x]; sb[threadIdx.x] = gb[threadIdx.x]; }
    if (threadIdx.x < NGROUPS) {
        smean[threadIdx.x] = stats[(b * NGROUPS + threadIdx.x) * 2];
        srstd[threadIdx.x] = stats[(b * NGROUPS + threadIdx.x) * 2 + 1];
    }
    __syncthreads();
    for (int it = 0; it < 64; ++it) {
        int idx = it * 256 + threadIdx.x;
        int c = idx >> 6, hwl = idx & 63;
        size_t g = ((size_t)b * CH + c) * HWSZ + hw0 + hwl;
        float v = x[g];
        int grp = c >> 5;
        float xn = (v - smean[grp]) * srstd[grp] * sw[c] + sb[c];
        xnf[g] = xn;
        lds[hwl * TPAD + c] = f2bf(xn);
    }
    __syncthreads();
    int hwl = threadIdx.x >> 2, cb = (threadIdx.x & 3) * 64;
    u16* dst = xnt + ((size_t)b * HWSZ + hw0 + hwl) * CH + cb;
    for (int j = 0; j < 64; j += 8) {
        u16 tmp[8];
        #pragma unroll
        for (int k = 0; k < 8; ++k) tmp[k] = lds[hwl * TPAD + cb + j + k];
        *(u32x4*)(dst + j) = *(u32x4*)tmp;
    }
}

// ---------------------------------------------------------------- QKV GEMM
// QKV[o,n] = sum_c W[o,c]*XNT[n,c] ; Q,K -> [b][n][c] bf16 ; V -> [b][c][n] bf16
__global__ __launch_bounds__(256) void qkv_gemm_k(const float* __restrict__ w,
                                                  const float* __restrict__ bias,
                                                  const u16* __restrict__ xnt,
                                                  u16* __restrict__ qws,
                                                  u16* __restrict__ kws,
                                                  u16* __restrict__ vws) {
    int b = blockIdx.z;
    int o0 = blockIdx.y * 64;
    int n0 = blockIdx.x * 64;
    int w_id = threadIdx.x >> 6;
    int lane = threadIdx.x & 63;
    int jr = lane & 15, g = lane >> 4;
    int orow = o0 + w_id * 16 + jr;
    f32x4 acc[4] = {};
    for (int kk = 0; kk < 8; ++kk) {
        const float* ap = w + (size_t)orow * CH + kk * 32 + g * 8;
        Frag8 af;
        #pragma unroll
        for (int e = 0; e < 8; ++e) af.s[e] = f2bf(ap[e]);
        #pragma unroll
        for (int s = 0; s < 4; ++s) {
            const u16* bp = xnt + ((size_t)b * HWSZ + n0 + s * 16 + jr) * CH + kk * 32 + g * 8;
            Frag8 bfr; bfr.q = *(const u32x4*)bp;
            acc[s] = __builtin_amdgcn_mfma_f32_16x16x32_bf16(af.v, bfr.v, acc[s], 0, 0, 0);
        }
    }
    #pragma unroll
    for (int s = 0; s < 4; ++s) {
        #pragma unroll
        for (int r = 0; r < 4; ++r) {
            int o = o0 + w_id * 16 + g * 4 + r;
            int n = n0 + s * 16 + jr;
            u16 bv = f2bf(acc[s][r] + bias[o]);
            if (o < 256)       qws[((size_t)b * HWSZ + n) * CH + o] = bv;
            else if (o < 512)  kws[((size_t)b * HWSZ + n) * CH + (o - 256)] = bv;
            else               vws[((size_t)b * CH + (o - 512)) * HWSZ + n] = bv;
        }
    }
}

// ---------------------------------------------------------------- Flash attention
// Q,K: [b][n][c] bf16 ; V: [b][c][n] bf16 ; O: [b][n][c] bf16
#define PSTRIDE 72
__global__ __launch_bounds__(256) void attn_k(const u16* __restrict__ qws,
                                              const u16* __restrict__ kws,
                                              const u16* __restrict__ vws,
                                              u16* __restrict__ ows) {
    int b = blockIdx.y;
    int q0 = blockIdx.x * 64;
    int w_id = threadIdx.x >> 6;
    int lane = threadIdx.x & 63;
    int jr = lane & 15, g = lane >> 4;
    __shared__ u16 plds[4][16 * PSTRIDE];

    Frag8 qa[8];
    const u16* qbase = qws + ((size_t)b * HWSZ + q0 + w_id * 16 + jr) * CH;
    #pragma unroll
    for (int kk = 0; kk < 8; ++kk) qa[kk].q = *(const u32x4*)(qbase + kk * 32 + g * 8);

    float m_run[4], l_run[4];
    #pragma unroll
    for (int r = 0; r < 4; ++r) { m_run[r] = -1e30f; l_run[r] = 0.f; }
    f32x4 acc[16] = {};
    const float scale = 0.0625f;  // 1/sqrt(256)

    for (int kt = 0; kt < 64; ++kt) {
        int k0 = kt * 64;
        f32x4 sacc[4] = {};
        #pragma unroll
        for (int kk = 0; kk < 8; ++kk) {
            #pragma unroll
            for (int s = 0; s < 4; ++s) {
                const u16* kp = kws + ((size_t)b * HWSZ + k0 + s * 16 + jr) * CH + kk * 32 + g * 8;
                Frag8 kf; kf.q = *(const u32x4*)kp;
                sacc[s] = __builtin_amdgcn_mfma_f32_16x16x32_bf16(qa[kk].v, kf.v, sacc[s], 0, 0, 0);
            }
        }
        float p[4][4];
        float alpha[4];
        #pragma unroll
        for (int r = 0; r < 4; ++r) {
            float t = fmaxf(fmaxf(sacc[0][r], sacc[1][r]), fmaxf(sacc[2][r], sacc[3][r])) * scale;
            #pragma unroll
            for (int off = 1; off < 16; off <<= 1) t = fmaxf(t, __shfl_xor(t, off, 64));
            float mnew = fmaxf(m_run[r], t);
            alpha[r] = __expf(m_run[r] - mnew);
            float rs = 0.f;
            #pragma unroll
            for (int s = 0; s < 4; ++s) {
                float pv = __expf(sacc[s][r] * scale - mnew);
                p[s][r] = pv;
                rs += pv;
            }
            #pragma unroll
            for (int off = 1; off < 16; off <<= 1) rs += __shfl_xor(rs, off, 64);
            l_run[r] = l_run[r] * alpha[r] + rs;
            m_run[r] = mnew;
        }
        #pragma unroll
        for (int cs = 0; cs < 16; ++cs) {
            #pragma unroll
            for (int r = 0; r < 4; ++r) acc[cs][r] *= alpha[r];
        }
        #pragma unroll
        for (int s = 0; s < 4; ++s) {
            #pragma unroll
            for (int r = 0; r < 4; ++r)
                plds[w_id][(g * 4 + r) * PSTRIDE + s * 16 + jr] = f2bf(p[s][r]);
        }
        __syncthreads();
        #pragma unroll
        for (int mm = 0; mm < 2; ++mm) {
            Frag8 pa;
            pa.q = *(const u32x4*)&plds[w_id][jr * PSTRIDE + mm * 32 + g * 8];
            #pragma unroll
            for (int cs = 0; cs < 16; ++cs) {
                const u16* vp = vws + ((size_t)b * CH + cs * 16 + jr) * HWSZ + k0 + mm * 32 + g * 8;
                Frag8 vf; vf.q = *(const u32x4*)vp;
                acc[cs] = __builtin_amdgcn_mfma_f32_16x16x32_bf16(pa.v, vf.v, acc[cs], 0, 0, 0);
            }
        }
        __syncthreads();
    }
    #pragma unroll
    for (int cs = 0; cs < 16; ++cs) {
        #pragma unroll
        for (int r = 0; r < 4; ++r) {
            int qrow = q0 + w_id * 16 + g * 4 + r;
            float val = acc[cs][r] / l_run[r];
            ows[((size_t)b * HWSZ + qrow) * CH + cs * 16 + jr] = f2bf(val);
        }
    }
}

// ---------------------------------------------------------------- out projection + residual
__global__ __launch_bounds__(256) void proj_k(const float* __restrict__ w,
                                              const float* __restrict__ bias,
                                              const u16* __restrict__ ows,
                                              const float* __restrict__ xnf,
                                              float* __restrict__ out) {
    int b = blockIdx.z;
    int o0 = blockIdx.y * 64;
    int n0 = blockIdx.x * 64;
    int w_id = threadIdx.x >> 6;
    int lane = threadIdx.x & 63;
    int jr = lane & 15, g = lane >> 4;
    int orow = o0 + w_id * 16 + jr;
    f32x4 acc[4] = {};
    for (int kk = 0; kk < 8; ++kk) {
        const float* ap = w + (size_t)orow * CH + kk * 32 + g * 8;
        Frag8 af;
        #pragma unroll
        for (int e = 0; e < 8; ++e) af.s[e] = f2bf(ap[e]);
        #pragma unroll
        for (int s = 0; s < 4; ++s) {
            const u16* bp = ows + ((size_t)b * HWSZ + n0 + s * 16 + jr) * CH + kk * 32 + g * 8;
            Frag8 bfr; bfr.q = *(const u32x4*)bp;
            acc[s] = __builtin_amdgcn_mfma_f32_16x16x32_bf16(af.v, bfr.v, acc[s], 0, 0, 0);
        }
    }
    #pragma unroll
    for (int s = 0; s < 4; ++s) {
        #pragma unroll
        for (int r = 0; r < 4; ++r) {
            int o = o0 + w_id * 16 + g * 4 + r;
            int n = n0 + s * 16 + jr;
            size_t gaddr = ((size_t)b * CH + o) * HWSZ + n;
            out[gaddr] = acc[s][r] + bias[o] + xnf[gaddr];
        }
    }
}

// ---------------------------------------------------------------- launch
extern "C" void kernel_launch(void* const* d_in, const int* in_sizes, int n_in,
                              void* d_out, int out_size, void* d_ws, size_t ws_size,
                              hipStream_t stream) {
    const float* x     = (const float*)d_in[0];
    const float* gn_w  = (const float*)d_in[1];
    const float* gn_b  = (const float*)d_in[2];
    const float* qkv_w = (const float*)d_in[3];
    const float* qkv_b = (const float*)d_in[4];
    const float* out_w = (const float*)d_in[5];
    const float* out_b = (const float*)d_in[6];
    float* out = (float*)d_out;

    char* ws = (char*)d_ws;
    const size_t NB = (size_t)BATCH * HWSZ * CH;  // 8M elements
    float* stats = (float*)ws;                        // 1 KiB
    float* xnf   = (float*)(ws + 1024);               // 32 MB
    size_t off = 1024 + NB * 4;
    u16* xnt = (u16*)(ws + off); off += NB * 2;       // 16 MB
    u16* qws = (u16*)(ws + off); off += NB * 2;
    u16* kws = (u16*)(ws + off); off += NB * 2;
    u16* vws = (u16*)(ws + off); off += NB * 2;
    u16* ows = (u16*)(ws + off); off += NB * 2;

    gn_stats_k<<<dim3(64), dim3(256), 0, stream>>>(x, stats);
    gn_apply_k<<<dim3(512), dim3(256), 0, stream>>>(x, stats, gn_w, gn_b, xnf, xnt);
    qkv_gemm_k<<<dim3(64, 12, 8), dim3(256), 0, stream>>>(qkv_w, qkv_b, xnt, qws, kws, vws);
    attn_k<<<dim3(64, 8), dim3(256), 0, stream>>>(qws, kws, vws, ows);
    proj_k<<<dim3(64, 4, 8), dim3(256), 0, stream>>>(out_w, out_b, ows, xnf, out);
}

// Round 2
// 663.130 us; speedup vs baseline: 1.9863x; 1.9863x over previous
//
#include <hip/hip_runtime.h>
#include <hip/hip_bf16.h>

#define BATCH 8
#define CH 256
#define HWSZ 4096
#define NGROUPS 8
#define CPG 32
#define GSIZE (CPG * HWSZ)  // 131072 elements per (b, group)

typedef unsigned short u16;
typedef short bf16x8 __attribute__((ext_vector_type(8)));   // 8 bf16 in 4 VGPRs
typedef float f32x4 __attribute__((ext_vector_type(4)));
typedef unsigned int u32x4 __attribute__((ext_vector_type(4)));

union Frag8 {
    bf16x8 v;
    u32x4 q;
    u16 s[8];
};

static __device__ inline u16 f2bf(float f) {
    unsigned int u = __float_as_uint(f);
    u = u + 0x7fffu + ((u >> 16) & 1u);   // round-to-nearest-even
    return (u16)(u >> 16);
}

// ---------------------------------------------------------------- GroupNorm stats
// pass 1: 512 blocks, partial (sum, sumsq) -> atomicAdd into partial[64*2]
__global__ __launch_bounds__(256) void gn_stats_part_k(const float* __restrict__ x,
                                                       float* __restrict__ partial) {
    int blk = blockIdx.x;            // 512 = 64 (b,g) * 8 chunks
    int bg = blk >> 3, chunk = blk & 7;
    const float4* base = (const float4*)(x + (size_t)bg * GSIZE + (size_t)chunk * (GSIZE / 8));
    float s = 0.f, ss = 0.f;
    for (int i = threadIdx.x; i < GSIZE / 8 / 4; i += 256) {
        float4 v = base[i];
        s += v.x + v.y + v.z + v.w;
        ss += v.x * v.x + v.y * v.y + v.z * v.z + v.w * v.w;
    }
    #pragma unroll
    for (int off = 32; off > 0; off >>= 1) {
        s += __shfl_xor(s, off, 64);
        ss += __shfl_xor(ss, off, 64);
    }
    __shared__ float red[8];
    int wid = threadIdx.x >> 6;
    if ((threadIdx.x & 63) == 0) { red[wid * 2] = s; red[wid * 2 + 1] = ss; }
    __syncthreads();
    if (threadIdx.x == 0) {
        float S = red[0] + red[2] + red[4] + red[6];
        float SS = red[1] + red[3] + red[5] + red[7];
        atomicAdd(&partial[bg * 2], S);
        atomicAdd(&partial[bg * 2 + 1], SS);
    }
}

__global__ void gn_finalize_k(const float* __restrict__ partial, float* __restrict__ stats) {
    int bg = threadIdx.x;  // 64
    float S = partial[bg * 2], SS = partial[bg * 2 + 1];
    float mean = S / (float)GSIZE;
    float var = SS / (float)GSIZE - mean * mean;
    stats[bg * 2] = mean;
    stats[bg * 2 + 1] = rsqrtf(var + 1e-5f);
}

// ---------------------------------------------------------------- GroupNorm apply
// writes xn f32 [b][c][hw] (residual) and xn bf16 transposed [b][hw][c]
#define TPAD 258
__global__ __launch_bounds__(256) void gn_apply_k(const float* __restrict__ x,
                                                  const float* __restrict__ stats,
                                                  const float* __restrict__ gw,
                                                  const float* __restrict__ gb,
                                                  float* __restrict__ xnf,
                                                  u16* __restrict__ xnt) {
    int b = blockIdx.x >> 6;
    int hw0 = (blockIdx.x & 63) * 64;
    __shared__ u16 lds[64 * TPAD];
    __shared__ float sw[CH], sb[CH], smean[NGROUPS], srstd[NGROUPS];
    if (threadIdx.x < CH) { sw[threadIdx.x] = gw[threadIdx.x]; sb[threadIdx.x] = gb[threadIdx.x]; }
    if (threadIdx.x < NGROUPS) {
        smean[threadIdx.x] = stats[(b * NGROUPS + threadIdx.x) * 2];
        srstd[threadIdx.x] = stats[(b * NGROUPS + threadIdx.x) * 2 + 1];
    }
    __syncthreads();
    for (int it = 0; it < 64; ++it) {
        int idx = it * 256 + threadIdx.x;
        int c = idx >> 6, hwl = idx & 63;
        size_t g = ((size_t)b * CH + c) * HWSZ + hw0 + hwl;
        float v = x[g];
        int grp = c >> 5;
        float xn = (v - smean[grp]) * srstd[grp] * sw[c] + sb[c];
        xnf[g] = xn;
        lds[hwl * TPAD + c] = f2bf(xn);
    }
    __syncthreads();
    int hwl = threadIdx.x >> 2, cb = (threadIdx.x & 3) * 64;
    u16* dst = xnt + ((size_t)b * HWSZ + hw0 + hwl) * CH + cb;
    for (int j = 0; j < 64; j += 8) {
        u16 tmp[8];
        #pragma unroll
        for (int k = 0; k < 8; ++k) tmp[k] = lds[hwl * TPAD + cb + j + k];
        *(u32x4*)(dst + j) = *(u32x4*)tmp;
    }
}

// ---------------------------------------------------------------- QKV GEMM
// QKV[o,n] = sum_c W[o,c]*XNT[n,c] ; Q,K -> [b][n][c] bf16 ; V -> [b][c][n] bf16
__global__ __launch_bounds__(256) void qkv_gemm_k(const float* __restrict__ w,
                                                  const float* __restrict__ bias,
                                                  const u16* __restrict__ xnt,
                                                  u16* __restrict__ qws,
                                                  u16* __restrict__ kws,
                                                  u16* __restrict__ vws) {
    int b = blockIdx.z;
    int o0 = blockIdx.y * 64;
    int n0 = blockIdx.x * 64;
    int w_id = threadIdx.x >> 6;
    int lane = threadIdx.x & 63;
    int jr = lane & 15, g = lane >> 4;
    int orow = o0 + w_id * 16 + jr;
    f32x4 acc[4] = {};
    for (int kk = 0; kk < 8; ++kk) {
        const float* ap = w + (size_t)orow * CH + kk * 32 + g * 8;
        Frag8 af;
        #pragma unroll
        for (int e = 0; e < 8; ++e) af.s[e] = f2bf(ap[e]);
        #pragma unroll
        for (int s = 0; s < 4; ++s) {
            const u16* bp = xnt + ((size_t)b * HWSZ + n0 + s * 16 + jr) * CH + kk * 32 + g * 8;
            Frag8 bfr; bfr.q = *(const u32x4*)bp;
            acc[s] = __builtin_amdgcn_mfma_f32_16x16x32_bf16(af.v, bfr.v, acc[s], 0, 0, 0);
        }
    }
    #pragma unroll
    for (int s = 0; s < 4; ++s) {
        #pragma unroll
        for (int r = 0; r < 4; ++r) {
            int o = o0 + w_id * 16 + g * 4 + r;
            int n = n0 + s * 16 + jr;
            u16 bv = f2bf(acc[s][r] + bias[o]);
            if (o < 256)       qws[((size_t)b * HWSZ + n) * CH + o] = bv;
            else if (o < 512)  kws[((size_t)b * HWSZ + n) * CH + (o - 256)] = bv;
            else               vws[((size_t)b * CH + (o - 512)) * HWSZ + n] = bv;
        }
    }
}

// ---------------------------------------------------------------- Flash attention
// Q,K: [b][n][c] bf16 ; V: [b][c][n] bf16 ; O: [b][n][c] bf16
// K tile staged in LDS [64][256] (row 512B) with byte-XOR swizzle (row&7)<<4
// V tile staged in LDS [256][64] (row 128B) with byte-XOR swizzle (row&7)<<4
// Double-buffered; global_load_lds(16B); counted vmcnt; raw barriers.
#define PSTRIDE 72
__global__ __launch_bounds__(256) void attn_k(const u16* __restrict__ qws,
                                              const u16* __restrict__ kws,
                                              const u16* __restrict__ vws,
                                              u16* __restrict__ ows) {
    __shared__ u16 kbuf[2][64 * 256];     // 2 x 32KB
    __shared__ u16 vbuf[2][256 * 64];     // 2 x 32KB
    __shared__ u16 plds[4][16 * PSTRIDE]; // 9KB, per-wave

    int b = blockIdx.y;
    int q0 = blockIdx.x * 64;
    int tid = threadIdx.x;
    int w_id = tid >> 6;
    int lane = tid & 63;
    int jr = lane & 15, g = lane >> 4;

    const char* kgbase = (const char*)(kws + ((size_t)b * HWSZ) * CH);
    const char* vgbase = (const char*)(vws + ((size_t)b * CH) * HWSZ);

    // Q fragments into registers (16 q-rows per wave)
    Frag8 qa[8];
    const u16* qbase = qws + ((size_t)b * HWSZ + q0 + w_id * 16 + jr) * CH;
    #pragma unroll
    for (int kk = 0; kk < 8; ++kk) qa[kk].q = *(const u32x4*)(qbase + kk * 32 + g * 8);

    // stage K+V tile kt into buffer bufi: 16 global_load_lds per wave
    auto stage = [&](int bufi, int kt) {
        int k0 = kt * 64;
        char* kd = (char*)&kbuf[bufi][0];
        char* vd = (char*)&vbuf[bufi][0];
        #pragma unroll
        for (int ii = 0; ii < 8; ++ii) {
            int i = w_id * 8 + ii;                 // K instr 0..31, 1KB each (2 rows x 512B)
            int r = i * 2 + (lane >> 5);
            int bl = (lane & 31) * 16;
            int bs = bl ^ ((r & 7) << 4);
            const char* src = kgbase + ((size_t)(k0 + r)) * 512 + bs;
            __builtin_amdgcn_global_load_lds(
                (const __attribute__((address_space(1))) void*)src,
                (__attribute__((address_space(3))) void*)(kd + i * 1024), 16, 0, 0);
        }
        #pragma unroll
        for (int ii = 0; ii < 8; ++ii) {
            int i = w_id * 8 + ii;                 // V instr 0..31, 1KB each (8 rows x 128B)
            int r = i * 8 + (lane >> 3);
            int bl = (lane & 7) * 16;
            int bs = bl ^ ((r & 7) << 4);
            const char* src = vgbase + (size_t)r * 8192 + (size_t)k0 * 2 + bs;
            __builtin_amdgcn_global_load_lds(
                (const __attribute__((address_space(1))) void*)src,
                (__attribute__((address_space(3))) void*)(vd + i * 1024), 16, 0, 0);
        }
    };

    float m_run[4], l_run[4];
    #pragma unroll
    for (int r = 0; r < 4; ++r) { m_run[r] = -1e30f; l_run[r] = 0.f; }
    f32x4 acc[16] = {};
    const float scale = 0.0625f;  // 1/sqrt(256)

    stage(0, 0);
    int bufi = 0;

    for (int kt = 0; kt < 64; ++kt) {
        if (kt + 1 < 64) {
            stage(bufi ^ 1, kt + 1);
            asm volatile("s_waitcnt vmcnt(16)" ::: "memory");  // this tile's 16 landed; next 16 in flight
        } else {
            asm volatile("s_waitcnt vmcnt(0)" ::: "memory");
        }
        __builtin_amdgcn_s_barrier();

        const char* kb = (const char*)&kbuf[bufi][0];
        const char* vb = (const char*)&vbuf[bufi][0];

        // ---- QK^T : S[16q x 64k] per wave
        f32x4 sacc[4] = {};
        #pragma unroll
        for (int kk = 0; kk < 8; ++kk) {
            #pragma unroll
            for (int s = 0; s < 4; ++s) {
                int r = s * 16 + jr;
                int cb = kk * 64 + g * 16;
                Frag8 kf; kf.q = *(const u32x4*)(kb + r * 512 + (cb ^ ((r & 7) << 4)));
                sacc[s] = __builtin_amdgcn_mfma_f32_16x16x32_bf16(qa[kk].v, kf.v, sacc[s], 0, 0, 0);
            }
        }

        // ---- online softmax (per-wave; 16-lane groups hold one q-row's 4 k-slices)
        float p[4][4];
        float alpha[4];
        #pragma unroll
        for (int r = 0; r < 4; ++r) {
            float t = fmaxf(fmaxf(sacc[0][r], sacc[1][r]), fmaxf(sacc[2][r], sacc[3][r])) * scale;
            #pragma unroll
            for (int off = 1; off < 16; off <<= 1) t = fmaxf(t, __shfl_xor(t, off, 64));
            float mnew = fmaxf(m_run[r], t);
            alpha[r] = __expf(m_run[r] - mnew);
            float rs = 0.f;
            #pragma unroll
            for (int s = 0; s < 4; ++s) {
                float pv = __expf(sacc[s][r] * scale - mnew);
                p[s][r] = pv;
                rs += pv;
            }
            #pragma unroll
            for (int off = 1; off < 16; off <<= 1) rs += __shfl_xor(rs, off, 64);
            l_run[r] = l_run[r] * alpha[r] + rs;
            m_run[r] = mnew;
        }
        #pragma unroll
        for (int cs = 0; cs < 16; ++cs) {
            #pragma unroll
            for (int r = 0; r < 4; ++r) acc[cs][r] *= alpha[r];
        }

        // ---- P -> per-wave LDS (re-layout to A-fragment); same-wave lgkm deps handled by compiler
        #pragma unroll
        for (int s = 0; s < 4; ++s) {
            #pragma unroll
            for (int r = 0; r < 4; ++r)
                plds[w_id][(g * 4 + r) * PSTRIDE + s * 16 + jr] = f2bf(p[s][r]);
        }

        // ---- PV : O[16q x 256c] accumulate
        #pragma unroll
        for (int mm = 0; mm < 2; ++mm) {
            Frag8 pa;
            pa.q = *(const u32x4*)&plds[w_id][jr * PSTRIDE + mm * 32 + g * 8];
            #pragma unroll
            for (int cs = 0; cs < 16; ++cs) {
                int r = cs * 16 + jr;
                int cb = mm * 64 + g * 16;
                Frag8 vf; vf.q = *(const u32x4*)(vb + r * 128 + (cb ^ ((r & 7) << 4)));
                acc[cs] = __builtin_amdgcn_mfma_f32_16x16x32_bf16(pa.v, vf.v, acc[cs], 0, 0, 0);
            }
        }

        asm volatile("s_waitcnt lgkmcnt(0)" ::: "memory");  // all LDS reads of this buffer done
        __builtin_amdgcn_s_barrier();
        bufi ^= 1;
    }

    #pragma unroll
    for (int cs = 0; cs < 16; ++cs) {
        #pragma unroll
        for (int r = 0; r < 4; ++r) {
            int qrow = q0 + w_id * 16 + g * 4 + r;
            float val = acc[cs][r] / l_run[r];
            ows[((size_t)b * HWSZ + qrow) * CH + cs * 16 + jr] = f2bf(val);
        }
    }
}

// ---------------------------------------------------------------- out projection + residual
__global__ __launch_bounds__(256) void proj_k(const float* __restrict__ w,
                                              const float* __restrict__ bias,
                                              const u16* __restrict__ ows,
                                              const float* __restrict__ xnf,
                                              float* __restrict__ out) {
    int b = blockIdx.z;
    int o0 = blockIdx.y * 64;
    int n0 = blockIdx.x * 64;
    int w_id = threadIdx.x >> 6;
    int lane = threadIdx.x & 63;
    int jr = lane & 15, g = lane >> 4;
    int orow = o0 + w_id * 16 + jr;
    f32x4 acc[4] = {};
    for (int kk = 0; kk < 8; ++kk) {
        const float* ap = w + (size_t)orow * CH + kk * 32 + g * 8;
        Frag8 af;
        #pragma unroll
        for (int e = 0; e < 8; ++e) af.s[e] = f2bf(ap[e]);
        #pragma unroll
        for (int s = 0; s < 4; ++s) {
            const u16* bp = ows + ((size_t)b * HWSZ + n0 + s * 16 + jr) * CH + kk * 32 + g * 8;
            Frag8 bfr; bfr.q = *(const u32x4*)bp;
            acc[s] = __builtin_amdgcn_mfma_f32_16x16x32_bf16(af.v, bfr.v, acc[s], 0, 0, 0);
        }
    }
    #pragma unroll
    for (int s = 0; s < 4; ++s) {
        #pragma unroll
        for (int r = 0; r < 4; ++r) {
            int o = o0 + w_id * 16 + g * 4 + r;
            int n = n0 + s * 16 + jr;
            size_t gaddr = ((size_t)b * CH + o) * HWSZ + n;
            out[gaddr] = acc[s][r] + bias[o] + xnf[gaddr];
        }
    }
}

// ---------------------------------------------------------------- launch
extern "C" void kernel_launch(void* const* d_in, const int* in_sizes, int n_in,
                              void* d_out, int out_size, void* d_ws, size_t ws_size,
                              hipStream_t stream) {
    const float* x     = (const float*)d_in[0];
    const float* gn_w  = (const float*)d_in[1];
    const float* gn_b  = (const float*)d_in[2];
    const float* qkv_w = (const float*)d_in[3];
    const float* qkv_b = (const float*)d_in[4];
    const float* out_w = (const float*)d_in[5];
    const float* out_b = (const float*)d_in[6];
    float* out = (float*)d_out;

    char* ws = (char*)d_ws;
    const size_t NB = (size_t)BATCH * HWSZ * CH;  // 8M elements
    float* stats   = (float*)ws;                      // 512B
    float* partial = (float*)(ws + 512);              // 512B
    float* xnf     = (float*)(ws + 1024);             // 32 MB
    size_t off = 1024 + NB * 4;
    u16* xnt = (u16*)(ws + off); off += NB * 2;       // 16 MB each
    u16* qws = (u16*)(ws + off); off += NB * 2;
    u16* kws = (u16*)(ws + off); off += NB * 2;
    u16* vws = (u16*)(ws + off); off += NB * 2;
    u16* ows = (u16*)(ws + off); off += NB * 2;

    hipMemsetAsync(partial, 0, 64 * 2 * sizeof(float), stream);
    gn_stats_part_k<<<dim3(512), dim3(256), 0, stream>>>(x, partial);
    gn_finalize_k<<<dim3(1), dim3(64), 0, stream>>>(partial, stats);
    gn_apply_k<<<dim3(512), dim3(256), 0, stream>>>(x, stats, gn_w, gn_b, xnf, xnt);
    qkv_gemm_k<<<dim3(64, 12, 8), dim3(256), 0, stream>>>(qkv_w, qkv_b, xnt, qws, kws, vws);
    attn_k<<<dim3(64, 8), dim3(256), 0, stream>>>(qws, kws, vws, ows);
    proj_k<<<dim3(64, 4, 8), dim3(256), 0, stream>>>(out_w, out_b, ows, xnf, out);
}

// Round 9
// 484.271 us; speedup vs baseline: 2.7199x; 1.3693x over previous
//
#include <hip/hip_runtime.h>
#include <hip/hip_bf16.h>

#define BATCH 8
#define CH 256
#define HWSZ 4096
#define NGROUPS 8
#define CPG 32
#define GSIZE (CPG * HWSZ)  // 131072 elements per (b, group)

typedef unsigned short u16;
typedef short bf16x8 __attribute__((ext_vector_type(8)));   // 8 bf16 in 4 VGPRs
typedef float f32x4 __attribute__((ext_vector_type(4)));
typedef unsigned int u32x4 __attribute__((ext_vector_type(4)));

union Frag8 {
    bf16x8 v;
    u32x4 q;
    u16 s[8];
};

static __device__ inline u16 f2bf(float f) {
    unsigned int u = __float_as_uint(f);
    u = u + 0x7fffu + ((u >> 16) & 1u);   // round-to-nearest-even
    return (u16)(u >> 16);
}

static __device__ inline unsigned int pk2bf(float a, float b) {
    __hip_bfloat162 h2 = __float22bfloat162_rn(make_float2(a, b));
    unsigned int r;
    __builtin_memcpy(&r, &h2, 4);
    return r;
}

// ---------------------------------------------------------------- GroupNorm stats
__global__ __launch_bounds__(256) void gn_stats_part_k(const float* __restrict__ x,
                                                       float* __restrict__ partial) {
    int blk = blockIdx.x;            // 512 = 64 (b,g) * 8 chunks
    int bg = blk >> 3, chunk = blk & 7;
    const float4* base = (const float4*)(x + (size_t)bg * GSIZE + (size_t)chunk * (GSIZE / 8));
    float s = 0.f, ss = 0.f;
    for (int i = threadIdx.x; i < GSIZE / 8 / 4; i += 256) {
        float4 v = base[i];
        s += v.x + v.y + v.z + v.w;
        ss += v.x * v.x + v.y * v.y + v.z * v.z + v.w * v.w;
    }
    #pragma unroll
    for (int off = 32; off > 0; off >>= 1) {
        s += __shfl_xor(s, off, 64);
        ss += __shfl_xor(ss, off, 64);
    }
    __shared__ float red[8];
    int wid = threadIdx.x >> 6;
    if ((threadIdx.x & 63) == 0) { red[wid * 2] = s; red[wid * 2 + 1] = ss; }
    __syncthreads();
    if (threadIdx.x == 0) {
        float S = red[0] + red[2] + red[4] + red[6];
        float SS = red[1] + red[3] + red[5] + red[7];
        atomicAdd(&partial[bg * 2], S);
        atomicAdd(&partial[bg * 2 + 1], SS);
    }
}

__global__ void gn_finalize_k(const float* __restrict__ partial, float* __restrict__ stats) {
    int bg = threadIdx.x;  // 64
    float S = partial[bg * 2], SS = partial[bg * 2 + 1];
    float mean = S / (float)GSIZE;
    float var = SS / (float)GSIZE - mean * mean;
    stats[bg * 2] = mean;
    stats[bg * 2 + 1] = rsqrtf(var + 1e-5f);
}

// ---------------------------------------------------------------- GroupNorm apply
#define TPAD 258
__global__ __launch_bounds__(256) void gn_apply_k(const float* __restrict__ x,
                                                  const float* __restrict__ stats,
                                                  const float* __restrict__ gw,
                                                  const float* __restrict__ gb,
                                                  float* __restrict__ xnf,
                                                  u16* __restrict__ xnt) {
    int b = blockIdx.x >> 6;
    int hw0 = (blockIdx.x & 63) * 64;
    __shared__ u16 lds[64 * TPAD];
    __shared__ float sw[CH], sb[CH], smean[NGROUPS], srstd[NGROUPS];
    if (threadIdx.x < CH) { sw[threadIdx.x] = gw[threadIdx.x]; sb[threadIdx.x] = gb[threadIdx.x]; }
    if (threadIdx.x < NGROUPS) {
        smean[threadIdx.x] = stats[(b * NGROUPS + threadIdx.x) * 2];
        srstd[threadIdx.x] = stats[(b * NGROUPS + threadIdx.x) * 2 + 1];
    }
    __syncthreads();
    for (int it = 0; it < 64; ++it) {
        int idx = it * 256 + threadIdx.x;
        int c = idx >> 6, hwl = idx & 63;
        size_t g = ((size_t)b * CH + c) * HWSZ + hw0 + hwl;
        float v = x[g];
        int grp = c >> 5;
        float xn = (v - smean[grp]) * srstd[grp] * sw[c] + sb[c];
        xnf[g] = xn;
        lds[hwl * TPAD + c] = f2bf(xn);
    }
    __syncthreads();
    int hwl = threadIdx.x >> 2, cb = (threadIdx.x & 3) * 64;
    u16* dst = xnt + ((size_t)b * HWSZ + hw0 + hwl) * CH + cb;
    for (int j = 0; j < 64; j += 8) {
        u16 tmp[8];
        #pragma unroll
        for (int k = 0; k < 8; ++k) tmp[k] = lds[hwl * TPAD + cb + j + k];
        *(u32x4*)(dst + j) = *(u32x4*)tmp;
    }
}

// ---------------------------------------------------------------- QKV GEMM
// Q is pre-scaled by 1/16 (folded attention scale).
__global__ __launch_bounds__(256) void qkv_gemm_k(const float* __restrict__ w,
                                                  const float* __restrict__ bias,
                                                  const u16* __restrict__ xnt,
                                                  u16* __restrict__ qws,
                                                  u16* __restrict__ kws,
                                                  u16* __restrict__ vws) {
    int b = blockIdx.z;
    int o0 = blockIdx.y * 64;
    int n0 = blockIdx.x * 64;
    int w_id = threadIdx.x >> 6;
    int lane = threadIdx.x & 63;
    int jr = lane & 15, g = lane >> 4;
    int orow = o0 + w_id * 16 + jr;
    f32x4 acc[4] = {};
    for (int kk = 0; kk < 8; ++kk) {
        const float* ap = w + (size_t)orow * CH + kk * 32 + g * 8;
        Frag8 af;
        #pragma unroll
        for (int e = 0; e < 8; ++e) af.s[e] = f2bf(ap[e]);
        #pragma unroll
        for (int s = 0; s < 4; ++s) {
            const u16* bp = xnt + ((size_t)b * HWSZ + n0 + s * 16 + jr) * CH + kk * 32 + g * 8;
            Frag8 bfr; bfr.q = *(const u32x4*)bp;
            acc[s] = __builtin_amdgcn_mfma_f32_16x16x32_bf16(af.v, bfr.v, acc[s], 0, 0, 0);
        }
    }
    #pragma unroll
    for (int s = 0; s < 4; ++s) {
        #pragma unroll
        for (int r = 0; r < 4; ++r) {
            int o = o0 + w_id * 16 + g * 4 + r;
            int n = n0 + s * 16 + jr;
            float val = acc[s][r] + bias[o];
            if (o < 256)       qws[((size_t)b * HWSZ + n) * CH + o] = f2bf(val * 0.0625f);
            else if (o < 512)  kws[((size_t)b * HWSZ + n) * CH + (o - 256)] = f2bf(val);
            else               vws[((size_t)b * CH + (o - 512)) * HWSZ + n] = f2bf(val);
        }
    }
}

// ---------------------------------------------------------------- Flash attention
// 8 waves x 16 q-rows = 128 q per block. K,V double-buffered in LDS.
// Swapped-operand MFMAs: S^T = mfma(K,Q) -> lane holds full 16-val slice of
// one q-row (q=jr); O^T = mfma(V,P) -> alpha/l rescale lane-local.
#define PSTRIDE 72
#define NW 8
__global__ __launch_bounds__(512, 1) void attn_k(const u16* __restrict__ qws,
                                                 const u16* __restrict__ kws,
                                                 const u16* __restrict__ vws,
                                                 u16* __restrict__ ows) {
    __shared__ u16 kbuf[2][64 * 256];     // 2 x 32KB
    __shared__ u16 vbuf[2][256 * 64];     // 2 x 32KB
    __shared__ u16 plds[NW][16 * PSTRIDE]; // 18KB

    int b = blockIdx.y;
    int q0 = blockIdx.x * 128;
    int tid = threadIdx.x;
    int w_id = tid >> 6;
    int lane = tid & 63;
    int jr = lane & 15, g = lane >> 4;

    const char* kgbase = (const char*)(kws + ((size_t)b * HWSZ) * CH);
    const char* vgbase = (const char*)(vws + ((size_t)b * CH) * HWSZ);

    // Q fragments (pre-scaled by 1/16): lane jr holds q-row (q0 + w*16 + jr)
    Frag8 qa[8];
    const u16* qbase = qws + ((size_t)b * HWSZ + q0 + w_id * 16 + jr) * CH;
    #pragma unroll
    for (int kk = 0; kk < 8; ++kk) qa[kk].q = *(const u32x4*)(qbase + kk * 32 + g * 8);

    // stage K+V tile kt into buffer bufi: 4 K-loads + 4 V-loads per wave
    auto stage = [&](int bufi, int kt) {
        int k0 = kt * 64;
        char* kd = (char*)&kbuf[bufi][0];
        char* vd = (char*)&vbuf[bufi][0];
        #pragma unroll
        for (int ii = 0; ii < 4; ++ii) {
            int i = w_id * 4 + ii;                 // 1KB each (2 rows x 512B)
            int r = i * 2 + (lane >> 5);
            int bl = (lane & 31) * 16;
            int bs = bl ^ ((r & 7) << 4);
            const char* src = kgbase + ((size_t)(k0 + r)) * 512 + bs;
            __builtin_amdgcn_global_load_lds(
                (const __attribute__((address_space(1))) void*)src,
                (__attribute__((address_space(3))) void*)(kd + i * 1024), 16, 0, 0);
        }
        #pragma unroll
        for (int ii = 0; ii < 4; ++ii) {
            int i = w_id * 4 + ii;                 // 1KB each (8 rows x 128B)
            int r = i * 8 + (lane >> 3);
            int bl = (lane & 7) * 16;
            int bs = bl ^ ((r & 7) << 4);
            const char* src = vgbase + (size_t)r * 8192 + (size_t)k0 * 2 + bs;
            __builtin_amdgcn_global_load_lds(
                (const __attribute__((address_space(1))) void*)src,
                (__attribute__((address_space(3))) void*)(vd + i * 1024), 16, 0, 0);
        }
    };

    float m_run = -1e30f, l_run = 0.f;
    f32x4 acc[16] = {};

    stage(0, 0);
    int bufi = 0;

    for (int kt = 0; kt < 64; ++kt) {
        if (kt + 1 < 64) {
            stage(bufi ^ 1, kt + 1);
            asm volatile("s_waitcnt vmcnt(8)" ::: "memory");  // this tile's 8 landed
        } else {
            asm volatile("s_waitcnt vmcnt(0)" ::: "memory");
        }
        __builtin_amdgcn_s_barrier();

        const char* kb = (const char*)&kbuf[bufi][0];
        const char* vb = (const char*)&vbuf[bufi][0];

        // ---- QK^T swapped: sacc[s] = K_s x Q -> lane holds k=s*16+g*4+r, q=jr
        f32x4 sacc[4] = {};
        __builtin_amdgcn_s_setprio(1);
        #pragma unroll
        for (int kk = 0; kk < 8; ++kk) {
            #pragma unroll
            for (int s = 0; s < 4; ++s) {
                int r = s * 16 + jr;
                int cb = kk * 64 + g * 16;
                Frag8 kf; kf.q = *(const u32x4*)(kb + r * 512 + (cb ^ ((r & 7) << 4)));
                sacc[s] = __builtin_amdgcn_mfma_f32_16x16x32_bf16(kf.v, qa[kk].v, sacc[s], 0, 0, 0);
            }
        }
        __builtin_amdgcn_s_setprio(0);

        // ---- online softmax: full row slice is in-lane; 2 shfls across g-dups
        float mx = sacc[0][0];
        #pragma unroll
        for (int s = 0; s < 4; ++s)
            #pragma unroll
            for (int r = 0; r < 4; ++r) mx = fmaxf(mx, sacc[s][r]);
        mx = fmaxf(mx, __shfl_xor(mx, 16, 64));
        mx = fmaxf(mx, __shfl_xor(mx, 32, 64));

        if (__any(mx > m_run + 8.f)) {       // defer-max: rescale only on growth
            float mnew = fmaxf(m_run, mx);
            float alpha = __expf(m_run - mnew);
            #pragma unroll
            for (int cs = 0; cs < 16; ++cs)
                #pragma unroll
                for (int r = 0; r < 4; ++r) acc[cs][r] *= alpha;
            l_run *= alpha;
            m_run = mnew;
        }

        float p[4][4];
        float rs = 0.f;
        #pragma unroll
        for (int s = 0; s < 4; ++s)
            #pragma unroll
            for (int r = 0; r < 4; ++r) {
                float pv = __expf(sacc[s][r] - m_run);
                p[s][r] = pv;
                rs += pv;
            }
        rs += __shfl_xor(rs, 16, 64);
        rs += __shfl_xor(rs, 32, 64);
        l_run += rs;

        // ---- P -> LDS (pack pairs): plds[w][q=jr][k=s*16+g*4+2i]
        #pragma unroll
        for (int s = 0; s < 4; ++s)
            #pragma unroll
            for (int i = 0; i < 2; ++i) {
                unsigned int pk = pk2bf(p[s][2 * i], p[s][2 * i + 1]);
                *(unsigned int*)&plds[w_id][jr * PSTRIDE + s * 16 + g * 4 + 2 * i] = pk;
            }

        // ---- PV swapped: acc[cs] = V_cs x P -> rows d=cs*16+g*4+r, cols q=jr
        __builtin_amdgcn_s_setprio(1);
        #pragma unroll
        for (int kk = 0; kk < 2; ++kk) {
            Frag8 pa;
            pa.q = *(const u32x4*)&plds[w_id][jr * PSTRIDE + kk * 32 + g * 8];
            #pragma unroll
            for (int cs = 0; cs < 16; ++cs) {
                int r = cs * 16 + jr;
                int cb = kk * 64 + g * 16;
                Frag8 vf; vf.q = *(const u32x4*)(vb + r * 128 + (cb ^ ((r & 7) << 4)));
                acc[cs] = __builtin_amdgcn_mfma_f32_16x16x32_bf16(vf.v, pa.v, acc[cs], 0, 0, 0);
            }
        }
        __builtin_amdgcn_s_setprio(0);

        asm volatile("s_waitcnt lgkmcnt(0)" ::: "memory");
        __builtin_amdgcn_s_barrier();
        bufi ^= 1;
    }

    // epilogue: acc holds O^T (rows d, cols q=jr); lane-local l
    float inv_l = 1.0f / l_run;
    int n = q0 + w_id * 16 + jr;
    u16* obase = ows + ((size_t)b * HWSZ + n) * CH;
    #pragma unroll
    for (int cs = 0; cs < 16; ++cs) {
        #pragma unroll
        for (int i = 0; i < 2; ++i) {
            int c = cs * 16 + g * 4 + 2 * i;
            unsigned int pk = pk2bf(acc[cs][2 * i] * inv_l, acc[cs][2 * i + 1] * inv_l);
            *(unsigned int*)&obase[c] = pk;
        }
    }
}

// ---------------------------------------------------------------- out projection + residual
__global__ __launch_bounds__(256) void proj_k(const float* __restrict__ w,
                                              const float* __restrict__ bias,
                                              const u16* __restrict__ ows,
                                              const float* __restrict__ xnf,
                                              float* __restrict__ out) {
    int b = blockIdx.z;
    int o0 = blockIdx.y * 64;
    int n0 = blockIdx.x * 64;
    int w_id = threadIdx.x >> 6;
    int lane = threadIdx.x & 63;
    int jr = lane & 15, g = lane >> 4;
    int orow = o0 + w_id * 16 + jr;
    f32x4 acc[4] = {};
    for (int kk = 0; kk < 8; ++kk) {
        const float* ap = w + (size_t)orow * CH + kk * 32 + g * 8;
        Frag8 af;
        #pragma unroll
        for (int e = 0; e < 8; ++e) af.s[e] = f2bf(ap[e]);
        #pragma unroll
        for (int s = 0; s < 4; ++s) {
            const u16* bp = ows + ((size_t)b * HWSZ + n0 + s * 16 + jr) * CH + kk * 32 + g * 8;
            Frag8 bfr; bfr.q = *(const u32x4*)bp;
            acc[s] = __builtin_amdgcn_mfma_f32_16x16x32_bf16(af.v, bfr.v, acc[s], 0, 0, 0);
        }
    }
    #pragma unroll
    for (int s = 0; s < 4; ++s) {
        #pragma unroll
        for (int r = 0; r < 4; ++r) {
            int o = o0 + w_id * 16 + g * 4 + r;
            int n = n0 + s * 16 + jr;
            size_t gaddr = ((size_t)b * CH + o) * HWSZ + n;
            out[gaddr] = acc[s][r] + bias[o] + xnf[gaddr];
        }
    }
}

// ---------------------------------------------------------------- launch
extern "C" void kernel_launch(void* const* d_in, const int* in_sizes, int n_in,
                              void* d_out, int out_size, void* d_ws, size_t ws_size,
                              hipStream_t stream) {
    const float* x     = (const float*)d_in[0];
    const float* gn_w  = (const float*)d_in[1];
    const float* gn_b  = (const float*)d_in[2];
    const float* qkv_w = (const float*)d_in[3];
    const float* qkv_b = (const float*)d_in[4];
    const float* out_w = (const float*)d_in[5];
    const float* out_b = (const float*)d_in[6];
    float* out = (float*)d_out;

    char* ws = (char*)d_ws;
    const size_t NB = (size_t)BATCH * HWSZ * CH;  // 8M elements
    float* stats   = (float*)ws;                      // 512B
    float* partial = (float*)(ws + 512);              // 512B
    float* xnf     = (float*)(ws + 1024);             // 32 MB
    size_t off = 1024 + NB * 4;
    u16* xnt = (u16*)(ws + off); off += NB * 2;       // 16 MB each
    u16* qws = (u16*)(ws + off); off += NB * 2;
    u16* kws = (u16*)(ws + off); off += NB * 2;
    u16* vws = (u16*)(ws + off); off += NB * 2;
    u16* ows = (u16*)(ws + off); off += NB * 2;

    hipMemsetAsync(partial, 0, 64 * 2 * sizeof(float), stream);
    gn_stats_part_k<<<dim3(512), dim3(256), 0, stream>>>(x, partial);
    gn_finalize_k<<<dim3(1), dim3(64), 0, stream>>>(partial, stats);
    gn_apply_k<<<dim3(512), dim3(256), 0, stream>>>(x, stats, gn_w, gn_b, xnf, xnt);
    qkv_gemm_k<<<dim3(64, 12, 8), dim3(256), 0, stream>>>(qkv_w, qkv_b, xnt, qws, kws, vws);
    attn_k<<<dim3(32, 8), dim3(512), 0, stream>>>(qws, kws, vws, ows);
    proj_k<<<dim3(64, 4, 8), dim3(256), 0, stream>>>(out_w, out_b, ows, xnf, out);
}